// Round 5
// baseline (136.316 us; speedup 1.0000x reference)
//
#include <hip/hip_runtime.h>
#include <hip/hip_bf16.h>

// ---------------------------------------------------------------------------
// Model: [gcn+fcg fused] || [conv1+conv2 fused, MFMA] -> fcc(MFMA) -> head
// B=64, K(nodes)=128, N_BAND=5, HW=128, CH=16
// ---------------------------------------------------------------------------

#define NROWS   8192      // B*K
#define IMG     16384     // 128*128
#define FCC_K   262144    // 16*128*128
#define FCC_BLOCKS 512
#define FCC_KRANGE 512    // FCC_K / FCC_BLOCKS
#define FCC_CHUNK 128     // K rows of W per LDS stage

typedef __attribute__((ext_vector_type(8))) short bf16x8;
typedef __attribute__((ext_vector_type(4))) float f32x4;
typedef __attribute__((ext_vector_type(4))) unsigned short us4;
typedef __attribute__((ext_vector_type(8))) unsigned short us8;

// RNE float->bf16 bits (finite inputs only)
__device__ __forceinline__ unsigned short f2bf(float f) {
    unsigned u = __float_as_uint(f);
    unsigned r = (u + 0x7FFFu + ((u >> 16) & 1u)) >> 16;
    return (unsigned short)r;
}

// ---------------------------------------------------------------------------
// Kernel 1: fused GCN chain + fcg. One block per batch row (64 blocks x 128).
// Rows 0..127 (= batch 0 exactly) get the column-mean treatment -> block-local.
// ---------------------------------------------------------------------------
__global__ __launch_bounds__(128) void gcnfcg_kernel(
    const float* __restrict__ x1,    // (8192,5)
    const float* __restrict__ W1,    // (5,10)
    const float* __restrict__ b1,    // (10)
    const float* __restrict__ W2,    // (10,1)
    const float* __restrict__ b2,    // (1)
    const float* __restrict__ fcgW,  // (128,128)
    const float* __restrict__ fcgb,  // (128)
    float* __restrict__ g)           // (64,128)
{
    __shared__ float sW1[50], sb1[10], sW2[10], smean[10];
    __shared__ float sy1[128][10];   // raw layer-1 rows (block 0 only)
    __shared__ float sh2[128];
    int b = blockIdx.x, t = threadIdx.x;
    if (t < 50) sW1[t] = W1[t];
    if (t < 10) { sb1[t] = b1[t]; sW2[t] = W2[t]; }
    __syncthreads();

    int r = b*128 + t;
    float x[5];
    #pragma unroll
    for (int f = 0; f < 5; ++f) x[f] = x1[r*5 + f];
    float y[10];
    #pragma unroll
    for (int o = 0; o < 10; ++o) {
        float a = 0.f;
        #pragma unroll
        for (int f = 0; f < 5; ++f) a += x[f] * sW1[f*10 + o];
        y[o] = a;
    }

    float h1row[10];
    if (b == 0) {
        #pragma unroll
        for (int o = 0; o < 10; ++o) sy1[t][o] = y[o];
        __syncthreads();
        if (t < 10) {
            float s = 0.f;
            for (int rr = 0; rr < 128; ++rr) s += sy1[rr][t];
            smean[t] = fmaxf(s * (1.f/128.f) + sb1[t], 0.f);
        }
        __syncthreads();
        #pragma unroll
        for (int o = 0; o < 10; ++o) h1row[o] = smean[o];
    } else {
        #pragma unroll
        for (int o = 0; o < 10; ++o) h1row[o] = fmaxf(y[o] + sb1[o], 0.f);
    }

    // layer 2 (10 -> 1). For b==0 all rows share h1row, so mean == value.
    float y2 = 0.f;
    #pragma unroll
    for (int o = 0; o < 10; ++o) y2 += h1row[o] * sW2[o];
    sh2[t] = fmaxf(y2 + b2[0], 0.f);
    __syncthreads();

    // fcg: g[b] = relu(h2_b @ fcgW + fcgb)
    float acc = fcgb[t];
    #pragma unroll 8
    for (int k = 0; k < 128; ++k) acc += sh2[k] * fcgW[k*128 + t];
    g[b*128 + t] = fmaxf(acc, 0.f);
}

// ---------------------------------------------------------------------------
// Kernel 2: fused conv1+conv2 (3x3 SAME, relu both) -> bf16 c2.
// Block: 1 image x 4 output rows. conv1 computed in-block into the LDS halo
// tile (6 rows incl. halo), then conv2 as 5x MFMA 16x16x32 per 16-px tile.
// ---------------------------------------------------------------------------
__global__ __launch_bounds__(256) void conv12_kernel(
    const float* __restrict__ x2,     // (64,128,128)
    const float* __restrict__ w1,     // (16,1,3,3)
    const float* __restrict__ b1,     // (16)
    const float* __restrict__ w2,     // (16,16,3,3)
    const float* __restrict__ b2,     // (16)
    unsigned short* __restrict__ c2bf)// (64,16,128,128) bf16
{
    __shared__ float sx2[8][130];             // 4,160 B  x2 tile (+halo)
    __shared__ unsigned short sin[6*130*16];  // 24,960 B conv1 out [rr][cc][ic]
    __shared__ unsigned short sB[5*512];      // 5,120 B  conv2 B-frags
    __shared__ float sw1[144], sb1v[16];

    int tid = threadIdx.x;
    int blk = blockIdx.x;                     // 64 images * 32 row-groups
    int b   = blk >> 5;
    int R0  = (blk & 31) * 4;

    if (tid < 144) sw1[tid] = w1[tid];
    if (tid < 16)  sb1v[tid] = b1[tid];

    // pack conv2 B-frags: sB[q][lane][e] = w2[oc=lane&15][ic=k&15][dd=2q+(k>>4)]
    for (int idx = tid; idx < 2560; idx += 256) {
        int q   = idx >> 9;
        int rem = idx & 511;
        int l   = rem >> 3;
        int e   = rem & 7;
        int k   = (l >> 4) * 8 + e;    // 0..31
        int oc  = l & 15;
        int ic  = k & 15;
        int dd  = 2*q + (k >> 4);
        unsigned short bits = 0;
        if (dd < 9) bits = f2bf(w2[oc*144 + ic*9 + dd]);
        sB[idx] = bits;
    }
    // zero sin halo columns (cc=0 and cc=129)
    if (tid < 192) {
        int rr = tid >> 5, rem = tid & 31;
        int cc = (rem < 16) ? 0 : 129;
        sin[(rr*130 + cc)*16 + (rem & 15)] = 0;
    }
    // stage x2 rows R0-2 .. R0+5 (zero-padded)
    {
        const float* xb = x2 + (size_t)b * IMG;
        for (int idx = tid; idx < 8*130; idx += 256) {
            int rr = idx / 130, cc = idx - rr*130;
            int ri = R0 - 2 + rr, gj = cc - 1;
            float v = 0.f;
            if (ri >= 0 && ri < 128 && gj >= 0 && gj < 128)
                v = xb[ri*128 + gj];
            sx2[rr][cc] = v;
        }
    }
    __syncthreads();

    // conv1: 6 rows (R0-1..R0+4) x 128 cols x 16 oc -> sin (bf16)
    for (int p = tid; p < 768; p += 256) {
        int rr = p >> 7;            // 0..5 ; conv1 output row = R0-1+rr
        int cc = p & 127;
        int ri1 = R0 - 1 + rr;
        bool valid = (ri1 >= 0 && ri1 < 128);
        float in9[3][3];
        #pragma unroll
        for (int di = 0; di < 3; ++di)
          #pragma unroll
          for (int dj = 0; dj < 3; ++dj)
              in9[di][dj] = sx2[rr + di][cc + dj];
        us8 o0, o1;
        #pragma unroll
        for (int oc = 0; oc < 16; ++oc) {
            float acc = sb1v[oc];
            #pragma unroll
            for (int di = 0; di < 3; ++di)
              #pragma unroll
              for (int dj = 0; dj < 3; ++dj)
                  acc += in9[di][dj] * sw1[oc*9 + di*3 + dj];
            unsigned short bits = valid ? f2bf(fmaxf(acc, 0.f)) : (unsigned short)0;
            if (oc < 8) o0[oc] = bits; else o1[oc - 8] = bits;
        }
        unsigned short* dst = &sin[(rr*130 + cc + 1)*16];
        *reinterpret_cast<us8*>(dst)     = o0;
        *reinterpret_cast<us8*>(dst + 8) = o1;
    }
    __syncthreads();

    // conv2 MFMA
    int lane = tid & 63;
    int wv   = tid >> 6;          // wave id -> output row R0+wv
    int ln   = lane & 15;
    int g    = lane >> 4;
    int ghalf = g & 1;

    int aoff[5];
    #pragma unroll
    for (int q = 0; q < 5; ++q) {
        int dd = 2*q + (g >> 1);
        if (dd > 8) dd = 8;       // B is zero there
        int di = dd / 3, dj = dd % 3;
        aoff[q] = ((wv + di)*130 + ln + dj)*16 + ghalf*8;
    }

    bf16x8 bf[5];
    #pragma unroll
    for (int q = 0; q < 5; ++q)
        bf[q] = *reinterpret_cast<const bf16x8*>(&sB[q*512 + lane*8]);

    float bias_oc = b2[ln];
    int r = R0 + wv;
    unsigned short* outbase = c2bf + ((size_t)b*16 + ln)*IMG + r*128;

    #pragma unroll
    for (int t = 0; t < 8; ++t) {
        f32x4 acc = {0.f, 0.f, 0.f, 0.f};
        #pragma unroll
        for (int q = 0; q < 5; ++q) {
            bf16x8 a = *reinterpret_cast<const bf16x8*>(&sin[aoff[q] + t*256]);
            acc = __builtin_amdgcn_mfma_f32_16x16x32_bf16(a, bf[q], acc, 0, 0, 0);
        }
        int pc = t*16 + g*4;
        #pragma unroll
        for (int reg = 0; reg < 4; ++reg)
            outbase[pc + reg] = f2bf(fmaxf(acc[reg] + bias_oc, 0.f));
    }
}

// ---------------------------------------------------------------------------
// Kernel 3: fcc split-K partials, bf16 MFMA. 512 blocks x K-slice 512.
// W staged in LDS in MFMA B-fragment order sWp[ks][j][lane][e] (lane rotated
// by +j to spread staging-write banks). Inner loop: 1 ds_read_b128 per MFMA.
// T14 async staging: next chunk's global loads issue before compute, LDS
// write after the barrier.
// ---------------------------------------------------------------------------
__global__ __launch_bounds__(256, 3) void fcc_mfma(
    const unsigned short* __restrict__ c2bf, // (64, 262144) bf16 row-major
    const float* __restrict__ W,             // (262144, 128) fp32
    float* __restrict__ partials)            // (512, 64*128)
{
    __shared__ unsigned short sWp[4*8*64*8];   // 32,768 B

    int tid  = threadIdx.x;
    int blk  = blockIdx.x;
    int k0   = blk * FCC_KRANGE;
    int lane = tid & 63, wv = tid >> 6;
    int ln   = lane & 15, g = lane >> 4;

    f32x4 acc[8];
    #pragma unroll
    for (int j = 0; j < 8; ++j) acc[j] = (f32x4){0.f,0.f,0.f,0.f};

    const float* Wb = W + (size_t)k0 * 128;
    const unsigned short* arow = c2bf + (size_t)(16*wv + ln)*FCC_K + k0 + g*8;

    float4 vbuf[16];

    // ---- prologue: load + write chunk 0 ----
    #pragma unroll
    for (int it = 0; it < 16; ++it) {
        int f = it*256 + tid;
        vbuf[it] = *reinterpret_cast<const float4*>(Wb + (size_t)(f >> 5)*128 + (f & 31)*4);
    }
    #pragma unroll
    for (int it = 0; it < 16; ++it) {
        int f = it*256 + tid;
        int k = f >> 5, col4 = f & 31;
        int kk = k & 31, ks = k >> 5, e = kk & 7, grp = kk >> 3;
        float vv[4] = {vbuf[it].x, vbuf[it].y, vbuf[it].z, vbuf[it].w};
        #pragma unroll
        for (int c = 0; c < 4; ++c) {
            int col = col4*4 + c;
            int j   = col >> 4;
            int l   = grp*16 + (col & 15);
            int ls  = (l + j) & 63;
            sWp[((ks*8 + j)*64 + ls)*8 + e] = f2bf(vv[c]);
        }
    }
    __syncthreads();

    // ---- main loop over 4 chunks of 128 K ----
    #pragma unroll
    for (int ci = 0; ci < 4; ++ci) {
        // issue next chunk's global loads (in flight across compute)
        if (ci < 3) {
            const float* Wc = Wb + (size_t)(ci + 1) * FCC_CHUNK * 128;
            #pragma unroll
            for (int it = 0; it < 16; ++it) {
                int f = it*256 + tid;
                vbuf[it] = *reinterpret_cast<const float4*>(Wc + (size_t)(f >> 5)*128 + (f & 31)*4);
            }
        }
        // prefetch all 4 A-fragments for this chunk
        bf16x8 af[4];
        #pragma unroll
        for (int ks = 0; ks < 4; ++ks)
            af[ks] = *reinterpret_cast<const bf16x8*>(arow + ci*FCC_CHUNK + ks*32);
        // compute: 16 K-steps of 32 -> 8 n-tiles each
        #pragma unroll
        for (int ks = 0; ks < 4; ++ks) {
            #pragma unroll
            for (int j = 0; j < 8; ++j) {
                bf16x8 bfrag = *reinterpret_cast<const bf16x8*>(
                    &sWp[((ks*8 + j)*64 + ((lane + j) & 63))*8]);
                acc[j] = __builtin_amdgcn_mfma_f32_16x16x32_bf16(af[ks], bfrag, acc[j], 0, 0, 0);
            }
        }
        __syncthreads();
        if (ci < 3) {
            #pragma unroll
            for (int it = 0; it < 16; ++it) {
                int f = it*256 + tid;
                int k = f >> 5, col4 = f & 31;
                int kk = k & 31, ks = k >> 5, e = kk & 7, grp = kk >> 3;
                float vv[4] = {vbuf[it].x, vbuf[it].y, vbuf[it].z, vbuf[it].w};
                #pragma unroll
                for (int c = 0; c < 4; ++c) {
                    int col = col4*4 + c;
                    int j   = col >> 4;
                    int l   = grp*16 + (col & 15);
                    int ls  = (l + j) & 63;
                    sWp[((ks*8 + j)*64 + ls)*8 + e] = f2bf(vv[c]);
                }
            }
            __syncthreads();
        }
    }

    float* p = partials + (size_t)blk * 8192;
    #pragma unroll
    for (int j = 0; j < 8; ++j)
      #pragma unroll
      for (int reg = 0; reg < 4; ++reg) {
          int m = 16*wv + g*4 + reg;
          p[m*128 + j*16 + ln] = acc[j][reg];
      }
}

// ---------------------------------------------------------------------------
// Kernel 4: head — reduce partials -> relu(+bias) = c ; concat(c,g) ->
// fc1 relu -> fc2 relu -> fc3 sigmoid. One block per batch row.
// ---------------------------------------------------------------------------
__global__ __launch_bounds__(128) void head_kernel(
    const float* __restrict__ partials, // (512, 64*128)
    const float* __restrict__ fccb,     // (128)
    const float* __restrict__ g,        // (64,128)
    const float* __restrict__ w1, const float* __restrict__ bb1,
    const float* __restrict__ w2, const float* __restrict__ bb2,
    const float* __restrict__ w3, const float* __restrict__ bb3,
    float* __restrict__ out)
{
    __shared__ float sx[256], sh[128], s2[64];
    int b = blockIdx.x, tid = threadIdx.x;

    // fused fcc_reduce: sum over 512 partial slices (coalesced 512-B rows)
    const float* pb = partials + (size_t)b*128 + tid;
    float s = 0.f;
    #pragma unroll 8
    for (int p = 0; p < FCC_BLOCKS; ++p) s += pb[(size_t)p*8192];
    sx[tid]       = fmaxf(s + fccb[tid], 0.f);
    sx[128 + tid] = g[b*128 + tid];
    __syncthreads();
    {
        float acc = bb1[tid];
        for (int k = 0; k < 256; ++k) acc += sx[k] * w1[k*128 + tid];
        sh[tid] = fmaxf(acc, 0.f);
    }
    __syncthreads();
    if (tid < 64) {
        float acc = bb2[tid];
        for (int k = 0; k < 128; ++k) acc += sh[k] * w2[k*64 + tid];
        s2[tid] = fmaxf(acc, 0.f);
    }
    __syncthreads();
    if (tid < 2) {
        float acc = bb3[tid];
        for (int k = 0; k < 64; ++k) acc += s2[k] * w3[k*2 + tid];
        out[b*2 + tid] = 1.f / (1.f + __expf(-acc));
    }
}

// ---------------------------------------------------------------------------
extern "C" void kernel_launch(void* const* d_in, const int* in_sizes, int n_in,
                              void* d_out, int out_size, void* d_ws, size_t ws_size,
                              hipStream_t stream)
{
    const float* x1      = (const float*)d_in[0];
    const float* x2      = (const float*)d_in[1];
    const float* gcn1_w  = (const float*)d_in[2];
    const float* gcn1_b  = (const float*)d_in[3];
    const float* gcn2_w  = (const float*)d_in[4];
    const float* gcn2_b  = (const float*)d_in[5];
    const float* fcg_w   = (const float*)d_in[6];
    const float* fcg_b   = (const float*)d_in[7];
    const float* conv1_w = (const float*)d_in[8];
    const float* conv1_b = (const float*)d_in[9];
    const float* conv2_w = (const float*)d_in[10];
    const float* conv2_b = (const float*)d_in[11];
    const float* fcc_w   = (const float*)d_in[12];
    const float* fcc_b   = (const float*)d_in[13];
    const float* fc1_w   = (const float*)d_in[14];
    const float* fc1_b   = (const float*)d_in[15];
    const float* fc2_w   = (const float*)d_in[16];
    const float* fc2_b   = (const float*)d_in[17];
    const float* fc3_w   = (const float*)d_in[18];
    const float* fc3_b   = (const float*)d_in[19];
    float* out = (float*)d_out;

    // workspace layout
    float* ws = (float*)d_ws;
    float* g        = ws;                          // 8,192 f
    unsigned short* c2bf = (unsigned short*)(g + 8192);   // 16,777,216 bf16
    float* partials = (float*)(c2bf + 16777216);   // 512*8192 = 4,194,304 f
    // total ~50.4 MB

    gcnfcg_kernel<<<64, 128, 0, stream>>>(x1, gcn1_w, gcn1_b, gcn2_w, gcn2_b,
                                          fcg_w, fcg_b, g);
    conv12_kernel<<<2048, 256, 0, stream>>>(x2, conv1_w, conv1_b,
                                            conv2_w, conv2_b, c2bf);
    fcc_mfma<<<FCC_BLOCKS, 256, 0, stream>>>(c2bf, fcc_w, partials);
    head_kernel<<<64, 128, 0, stream>>>(partials, fcc_b, g, fc1_w, fc1_b,
                                        fc2_w, fc2_b, fc3_w, fc3_b, out);
}

// Round 6
// 110.324 us; speedup vs baseline: 1.2356x; 1.2356x over previous
//
#include <hip/hip_runtime.h>
#include <hip/hip_bf16.h>

// ---------------------------------------------------------------------------
// Model: [gcn+fcg fused] || [conv1+conv2 fused, MFMA] -> fcc(MFMA) -> head
// B=64, K(nodes)=128, N_BAND=5, HW=128, CH=16
// ---------------------------------------------------------------------------

#define NROWS   8192      // B*K
#define IMG     16384     // 128*128
#define FCC_K   262144    // 16*128*128
#define FCC_BLOCKS 512
#define FCC_KRANGE 512    // FCC_K / FCC_BLOCKS
#define FCC_CHUNK 128     // K rows of W per LDS stage

typedef __attribute__((ext_vector_type(8))) short bf16x8;
typedef __attribute__((ext_vector_type(4))) float f32x4;
typedef __attribute__((ext_vector_type(4))) unsigned short us4;
typedef __attribute__((ext_vector_type(8))) unsigned short us8;

// RNE float->bf16 bits (finite inputs only)
__device__ __forceinline__ unsigned short f2bf(float f) {
    unsigned u = __float_as_uint(f);
    unsigned r = (u + 0x7FFFu + ((u >> 16) & 1u)) >> 16;
    return (unsigned short)r;
}

// ---------------------------------------------------------------------------
// Kernel 1: fused GCN chain + fcg. One block per batch row (64 blocks x 128).
// Rows 0..127 (= batch 0 exactly) get the column-mean treatment -> block-local.
// ---------------------------------------------------------------------------
__global__ __launch_bounds__(128) void gcnfcg_kernel(
    const float* __restrict__ x1,    // (8192,5)
    const float* __restrict__ W1,    // (5,10)
    const float* __restrict__ b1,    // (10)
    const float* __restrict__ W2,    // (10,1)
    const float* __restrict__ b2,    // (1)
    const float* __restrict__ fcgW,  // (128,128)
    const float* __restrict__ fcgb,  // (128)
    float* __restrict__ g)           // (64,128)
{
    __shared__ float sW1[50], sb1[10], sW2[10], smean[10];
    __shared__ float sy1[128][10];   // raw layer-1 rows (block 0 only)
    __shared__ float sh2[128];
    int b = blockIdx.x, t = threadIdx.x;
    if (t < 50) sW1[t] = W1[t];
    if (t < 10) { sb1[t] = b1[t]; sW2[t] = W2[t]; }
    __syncthreads();

    int r = b*128 + t;
    float x[5];
    #pragma unroll
    for (int f = 0; f < 5; ++f) x[f] = x1[r*5 + f];
    float y[10];
    #pragma unroll
    for (int o = 0; o < 10; ++o) {
        float a = 0.f;
        #pragma unroll
        for (int f = 0; f < 5; ++f) a += x[f] * sW1[f*10 + o];
        y[o] = a;
    }

    float h1row[10];
    if (b == 0) {
        #pragma unroll
        for (int o = 0; o < 10; ++o) sy1[t][o] = y[o];
        __syncthreads();
        if (t < 10) {
            float s = 0.f;
            for (int rr = 0; rr < 128; ++rr) s += sy1[rr][t];
            smean[t] = fmaxf(s * (1.f/128.f) + sb1[t], 0.f);
        }
        __syncthreads();
        #pragma unroll
        for (int o = 0; o < 10; ++o) h1row[o] = smean[o];
    } else {
        #pragma unroll
        for (int o = 0; o < 10; ++o) h1row[o] = fmaxf(y[o] + sb1[o], 0.f);
    }

    // layer 2 (10 -> 1). For b==0 all rows share h1row, so mean == value.
    float y2 = 0.f;
    #pragma unroll
    for (int o = 0; o < 10; ++o) y2 += h1row[o] * sW2[o];
    sh2[t] = fmaxf(y2 + b2[0], 0.f);
    __syncthreads();

    // fcg: g[b] = relu(h2_b @ fcgW + fcgb)
    float acc = fcgb[t];
    #pragma unroll 8
    for (int k = 0; k < 128; ++k) acc += sh2[k] * fcgW[k*128 + t];
    g[b*128 + t] = fmaxf(acc, 0.f);
}

// ---------------------------------------------------------------------------
// Kernel 2: fused conv1+conv2 (3x3 SAME, relu both) -> bf16 c2.
// Block: 1 image x 4 output rows. conv1 computed in-block into the LDS halo
// tile (6 rows incl. halo), then conv2 as 5x MFMA 16x16x32 per 16-px tile.
// ---------------------------------------------------------------------------
__global__ __launch_bounds__(256) void conv12_kernel(
    const float* __restrict__ x2,     // (64,128,128)
    const float* __restrict__ w1,     // (16,1,3,3)
    const float* __restrict__ b1,     // (16)
    const float* __restrict__ w2,     // (16,16,3,3)
    const float* __restrict__ b2,     // (16)
    unsigned short* __restrict__ c2bf)// (64,16,128,128) bf16
{
    __shared__ float sx2[8][130];             // 4,160 B  x2 tile (+halo)
    __shared__ unsigned short sin[6*130*16];  // 24,960 B conv1 out [rr][cc][ic]
    __shared__ unsigned short sB[5*512];      // 5,120 B  conv2 B-frags
    __shared__ float sw1[144], sb1v[16];

    int tid = threadIdx.x;
    int blk = blockIdx.x;                     // 64 images * 32 row-groups
    int b   = blk >> 5;
    int R0  = (blk & 31) * 4;

    if (tid < 144) sw1[tid] = w1[tid];
    if (tid < 16)  sb1v[tid] = b1[tid];

    // pack conv2 B-frags: sB[q][lane][e] = w2[oc=lane&15][ic=k&15][dd=2q+(k>>4)]
    for (int idx = tid; idx < 2560; idx += 256) {
        int q   = idx >> 9;
        int rem = idx & 511;
        int l   = rem >> 3;
        int e   = rem & 7;
        int k   = (l >> 4) * 8 + e;    // 0..31
        int oc  = l & 15;
        int ic  = k & 15;
        int dd  = 2*q + (k >> 4);
        unsigned short bits = 0;
        if (dd < 9) bits = f2bf(w2[oc*144 + ic*9 + dd]);
        sB[idx] = bits;
    }
    // zero sin halo columns (cc=0 and cc=129)
    if (tid < 192) {
        int rr = tid >> 5, rem = tid & 31;
        int cc = (rem < 16) ? 0 : 129;
        sin[(rr*130 + cc)*16 + (rem & 15)] = 0;
    }
    // stage x2 rows R0-2 .. R0+5 (zero-padded)
    {
        const float* xb = x2 + (size_t)b * IMG;
        for (int idx = tid; idx < 8*130; idx += 256) {
            int rr = idx / 130, cc = idx - rr*130;
            int ri = R0 - 2 + rr, gj = cc - 1;
            float v = 0.f;
            if (ri >= 0 && ri < 128 && gj >= 0 && gj < 128)
                v = xb[ri*128 + gj];
            sx2[rr][cc] = v;
        }
    }
    __syncthreads();

    // conv1: 6 rows (R0-1..R0+4) x 128 cols x 16 oc -> sin (bf16)
    for (int p = tid; p < 768; p += 256) {
        int rr = p >> 7;            // 0..5 ; conv1 output row = R0-1+rr
        int cc = p & 127;
        int ri1 = R0 - 1 + rr;
        bool valid = (ri1 >= 0 && ri1 < 128);
        float in9[3][3];
        #pragma unroll
        for (int di = 0; di < 3; ++di)
          #pragma unroll
          for (int dj = 0; dj < 3; ++dj)
              in9[di][dj] = sx2[rr + di][cc + dj];
        us8 o0, o1;
        #pragma unroll
        for (int oc = 0; oc < 16; ++oc) {
            float acc = sb1v[oc];
            #pragma unroll
            for (int di = 0; di < 3; ++di)
              #pragma unroll
              for (int dj = 0; dj < 3; ++dj)
                  acc += in9[di][dj] * sw1[oc*9 + di*3 + dj];
            unsigned short bits = valid ? f2bf(fmaxf(acc, 0.f)) : (unsigned short)0;
            if (oc < 8) o0[oc] = bits; else o1[oc - 8] = bits;
        }
        unsigned short* dst = &sin[(rr*130 + cc + 1)*16];
        *reinterpret_cast<us8*>(dst)     = o0;
        *reinterpret_cast<us8*>(dst + 8) = o1;
    }
    __syncthreads();

    // conv2 MFMA
    int lane = tid & 63;
    int wv   = tid >> 6;          // wave id -> output row R0+wv
    int ln   = lane & 15;
    int g    = lane >> 4;
    int ghalf = g & 1;

    int aoff[5];
    #pragma unroll
    for (int q = 0; q < 5; ++q) {
        int dd = 2*q + (g >> 1);
        if (dd > 8) dd = 8;       // B is zero there
        int di = dd / 3, dj = dd % 3;
        aoff[q] = ((wv + di)*130 + ln + dj)*16 + ghalf*8;
    }

    bf16x8 bf[5];
    #pragma unroll
    for (int q = 0; q < 5; ++q)
        bf[q] = *reinterpret_cast<const bf16x8*>(&sB[q*512 + lane*8]);

    float bias_oc = b2[ln];
    int r = R0 + wv;
    unsigned short* outbase = c2bf + ((size_t)b*16 + ln)*IMG + r*128;

    #pragma unroll
    for (int t = 0; t < 8; ++t) {
        f32x4 acc = {0.f, 0.f, 0.f, 0.f};
        #pragma unroll
        for (int q = 0; q < 5; ++q) {
            bf16x8 a = *reinterpret_cast<const bf16x8*>(&sin[aoff[q] + t*256]);
            acc = __builtin_amdgcn_mfma_f32_16x16x32_bf16(a, bf[q], acc, 0, 0, 0);
        }
        int pc = t*16 + g*4;
        #pragma unroll
        for (int reg = 0; reg < 4; ++reg)
            outbase[pc + reg] = f2bf(fmaxf(acc[reg] + bias_oc, 0.f));
    }
}

// ---------------------------------------------------------------------------
// Kernel 3: fcc split-K partials, bf16 MFMA. 512 blocks x K-slice 512.
// W chunk staged TRANSPOSED in LDS: sWt[col][k] bf16 with XOR swizzle
// idx = (col*128 + k) ^ ((col&7)<<3)  (short units).
//  - staging: thread loads 8 rows x float4 (coalesced), register-transposes
//    to 4 col-vectors, writes 4 ds_write_b128 (8 bf16 along k).
//  - compute: B-fragment = ONE ds_read_b128 (slot = col&7 -> conflict-free).
// Plain 2-barrier loop, no register prefetch buffer (R5 spill lesson).
// ---------------------------------------------------------------------------
__global__ __launch_bounds__(256, 3) void fcc_mfma(
    const unsigned short* __restrict__ c2bf, // (64, 262144) bf16 row-major
    const float* __restrict__ W,             // (262144, 128) fp32
    float* __restrict__ partials)            // (512, 64*128)
{
    __shared__ unsigned short sWt[128*128];   // 32 KB, transposed+swizzled

    int tid  = threadIdx.x;
    int blk  = blockIdx.x;
    int k0   = blk * FCC_KRANGE;
    int lane = tid & 63, wv = tid >> 6;
    int ln   = lane & 15, g = lane >> 4;

    int q  = tid & 31;      // staging col-quad (cols 4q..4q+3)
    int kO = tid >> 5;      // staging k-octet group 0..7

    f32x4 acc[8];
    #pragma unroll
    for (int j = 0; j < 8; ++j) acc[j] = (f32x4){0.f,0.f,0.f,0.f};

    const float* Wb = W + (size_t)k0 * 128;
    const unsigned short* arow = c2bf + (size_t)(16*wv + ln)*FCC_K + k0 + g*8;

    for (int ci = 0; ci < 4; ++ci) {
        // ---- stage chunk ci: W rows [ci*128, +128) -> sWt (transposed) ----
        const float* Wc = Wb + (size_t)ci * FCC_CHUNK * 128;
        #pragma unroll
        for (int ko2 = 0; ko2 < 2; ++ko2) {
            int kbase = ko2*64 + kO*8;
            float4 rows[8];
            #pragma unroll
            for (int r = 0; r < 8; ++r)
                rows[r] = *reinterpret_cast<const float4*>(
                    Wc + (size_t)(kbase + r)*128 + q*4);
            us8 vc0, vc1, vc2, vc3;
            #pragma unroll
            for (int r = 0; r < 8; ++r) {
                vc0[r] = f2bf(rows[r].x);
                vc1[r] = f2bf(rows[r].y);
                vc2[r] = f2bf(rows[r].z);
                vc3[r] = f2bf(rows[r].w);
            }
            int col0 = q*4;
            *reinterpret_cast<us8*>(&sWt[((col0+0)*128 + kbase) ^ (((col0+0)&7)<<3)]) = vc0;
            *reinterpret_cast<us8*>(&sWt[((col0+1)*128 + kbase) ^ (((col0+1)&7)<<3)]) = vc1;
            *reinterpret_cast<us8*>(&sWt[((col0+2)*128 + kbase) ^ (((col0+2)&7)<<3)]) = vc2;
            *reinterpret_cast<us8*>(&sWt[((col0+3)*128 + kbase) ^ (((col0+3)&7)<<3)]) = vc3;
        }
        __syncthreads();

        // ---- A-fragments for this chunk (global, L2/L3-resident) ----
        bf16x8 af[4];
        #pragma unroll
        for (int ks = 0; ks < 4; ++ks)
            af[ks] = *reinterpret_cast<const bf16x8*>(arow + ci*FCC_CHUNK + ks*32);

        // ---- compute: 4 K-steps of 32, 8 n-tiles each; 1 b128 per MFMA ----
        #pragma unroll
        for (int ks = 0; ks < 4; ++ks) {
            #pragma unroll
            for (int j = 0; j < 8; ++j) {
                int col = j*16 + ln;
                int idx = (col*128 + ks*32 + g*8) ^ ((col&7)<<3);
                bf16x8 bfrag = *reinterpret_cast<const bf16x8*>(&sWt[idx]);
                acc[j] = __builtin_amdgcn_mfma_f32_16x16x32_bf16(af[ks], bfrag, acc[j], 0, 0, 0);
            }
        }
        __syncthreads();
    }

    float* p = partials + (size_t)blk * 8192;
    #pragma unroll
    for (int j = 0; j < 8; ++j)
      #pragma unroll
      for (int reg = 0; reg < 4; ++reg) {
          int m = 16*wv + g*4 + reg;
          p[m*128 + j*16 + ln] = acc[j][reg];
      }
}

// ---------------------------------------------------------------------------
// Kernel 4: head — reduce partials -> relu(+bias) = c ; concat(c,g) ->
// fc1 relu -> fc2 relu -> fc3 sigmoid. One block per batch row.
// ---------------------------------------------------------------------------
__global__ __launch_bounds__(128) void head_kernel(
    const float* __restrict__ partials, // (512, 64*128)
    const float* __restrict__ fccb,     // (128)
    const float* __restrict__ g,        // (64,128)
    const float* __restrict__ w1, const float* __restrict__ bb1,
    const float* __restrict__ w2, const float* __restrict__ bb2,
    const float* __restrict__ w3, const float* __restrict__ bb3,
    float* __restrict__ out)
{
    __shared__ float sx[256], sh[128], s2[64];
    int b = blockIdx.x, tid = threadIdx.x;

    // fused fcc_reduce: sum over 512 partial slices (coalesced 512-B rows)
    const float* pb = partials + (size_t)b*128 + tid;
    float s = 0.f;
    #pragma unroll 8
    for (int p = 0; p < FCC_BLOCKS; ++p) s += pb[(size_t)p*8192];
    sx[tid]       = fmaxf(s + fccb[tid], 0.f);
    sx[128 + tid] = g[b*128 + tid];
    __syncthreads();
    {
        float acc = bb1[tid];
        for (int k = 0; k < 256; ++k) acc += sx[k] * w1[k*128 + tid];
        sh[tid] = fmaxf(acc, 0.f);
    }
    __syncthreads();
    if (tid < 64) {
        float acc = bb2[tid];
        for (int k = 0; k < 128; ++k) acc += sh[k] * w2[k*64 + tid];
        s2[tid] = fmaxf(acc, 0.f);
    }
    __syncthreads();
    if (tid < 2) {
        float acc = bb3[tid];
        for (int k = 0; k < 64; ++k) acc += s2[k] * w3[k*2 + tid];
        out[b*2 + tid] = 1.f / (1.f + __expf(-acc));
    }
}

// ---------------------------------------------------------------------------
extern "C" void kernel_launch(void* const* d_in, const int* in_sizes, int n_in,
                              void* d_out, int out_size, void* d_ws, size_t ws_size,
                              hipStream_t stream)
{
    const float* x1      = (const float*)d_in[0];
    const float* x2      = (const float*)d_in[1];
    const float* gcn1_w  = (const float*)d_in[2];
    const float* gcn1_b  = (const float*)d_in[3];
    const float* gcn2_w  = (const float*)d_in[4];
    const float* gcn2_b  = (const float*)d_in[5];
    const float* fcg_w   = (const float*)d_in[6];
    const float* fcg_b   = (const float*)d_in[7];
    const float* conv1_w = (const float*)d_in[8];
    const float* conv1_b = (const float*)d_in[9];
    const float* conv2_w = (const float*)d_in[10];
    const float* conv2_b = (const float*)d_in[11];
    const float* fcc_w   = (const float*)d_in[12];
    const float* fcc_b   = (const float*)d_in[13];
    const float* fc1_w   = (const float*)d_in[14];
    const float* fc1_b   = (const float*)d_in[15];
    const float* fc2_w   = (const float*)d_in[16];
    const float* fc2_b   = (const float*)d_in[17];
    const float* fc3_w   = (const float*)d_in[18];
    const float* fc3_b   = (const float*)d_in[19];
    float* out = (float*)d_out;

    // workspace layout
    float* ws = (float*)d_ws;
    float* g        = ws;                          // 8,192 f
    unsigned short* c2bf = (unsigned short*)(g + 8192);   // 16,777,216 bf16
    float* partials = (float*)(c2bf + 16777216);   // 512*8192 = 4,194,304 f
    // total ~50.4 MB

    gcnfcg_kernel<<<64, 128, 0, stream>>>(x1, gcn1_w, gcn1_b, gcn2_w, gcn2_b,
                                          fcg_w, fcg_b, g);
    conv12_kernel<<<2048, 256, 0, stream>>>(x2, conv1_w, conv1_b,
                                            conv2_w, conv2_b, c2bf);
    fcc_mfma<<<FCC_BLOCKS, 256, 0, stream>>>(c2bf, fcc_w, partials);
    head_kernel<<<64, 128, 0, stream>>>(partials, fcc_b, g, fc1_w, fc1_b,
                                        fc2_w, fc2_b, fc3_w, fc3_b, out);
}

// Round 7
// 96.223 us; speedup vs baseline: 1.4167x; 1.1465x over previous
//
#include <hip/hip_runtime.h>
#include <hip/hip_bf16.h>

// ---------------------------------------------------------------------------
// Model: [gcn+fcg fused] || [conv1+conv2 fused, MFMA] -> fcc(MFMA) -> head
// B=64, K(nodes)=128, N_BAND=5, HW=128, CH=16
// ---------------------------------------------------------------------------

#define NROWS   8192      // B*K
#define IMG     16384     // 128*128
#define FCC_K   262144    // 16*128*128
#define FCC_BLOCKS 512
#define FCC_KRANGE 512    // FCC_K / FCC_BLOCKS
#define FCC_CHUNK 128     // K rows of W per LDS stage

typedef __attribute__((ext_vector_type(8))) short bf16x8;
typedef __attribute__((ext_vector_type(4))) float f32x4;
typedef __attribute__((ext_vector_type(4))) unsigned short us4;
typedef __attribute__((ext_vector_type(8))) unsigned short us8;

// RNE float->bf16 bits (finite inputs only)
__device__ __forceinline__ unsigned short f2bf(float f) {
    unsigned u = __float_as_uint(f);
    unsigned r = (u + 0x7FFFu + ((u >> 16) & 1u)) >> 16;
    return (unsigned short)r;
}

// fcc LDS layout (shorts): both read- and write-side bank-conflict-free.
// idx = col*128 + (k ^ (slot<<3)), slot = (col ^ (col>>2)) & 15.
__device__ __forceinline__ int fcc_swz(int col, int k) {
    return col*128 + (k ^ ((((col >> 2) ^ col) & 15) << 3));
}

// ---------------------------------------------------------------------------
// Kernel 1: fused GCN chain + fcg. One block per batch row (64 blocks x 128).
// Rows 0..127 (= batch 0 exactly) get the column-mean treatment -> block-local.
// ---------------------------------------------------------------------------
__global__ __launch_bounds__(128) void gcnfcg_kernel(
    const float* __restrict__ x1,    // (8192,5)
    const float* __restrict__ W1,    // (5,10)
    const float* __restrict__ b1,    // (10)
    const float* __restrict__ W2,    // (10,1)
    const float* __restrict__ b2,    // (1)
    const float* __restrict__ fcgW,  // (128,128)
    const float* __restrict__ fcgb,  // (128)
    float* __restrict__ g)           // (64,128)
{
    __shared__ float sW1[50], sb1[10], sW2[10], smean[10];
    __shared__ float sy1[128][10];   // raw layer-1 rows (block 0 only)
    __shared__ float sh2[128];
    int b = blockIdx.x, t = threadIdx.x;
    if (t < 50) sW1[t] = W1[t];
    if (t < 10) { sb1[t] = b1[t]; sW2[t] = W2[t]; }
    __syncthreads();

    int r = b*128 + t;
    float x[5];
    #pragma unroll
    for (int f = 0; f < 5; ++f) x[f] = x1[r*5 + f];
    float y[10];
    #pragma unroll
    for (int o = 0; o < 10; ++o) {
        float a = 0.f;
        #pragma unroll
        for (int f = 0; f < 5; ++f) a += x[f] * sW1[f*10 + o];
        y[o] = a;
    }

    float h1row[10];
    if (b == 0) {
        #pragma unroll
        for (int o = 0; o < 10; ++o) sy1[t][o] = y[o];
        __syncthreads();
        if (t < 10) {
            float s = 0.f;
            for (int rr = 0; rr < 128; ++rr) s += sy1[rr][t];
            smean[t] = fmaxf(s * (1.f/128.f) + sb1[t], 0.f);
        }
        __syncthreads();
        #pragma unroll
        for (int o = 0; o < 10; ++o) h1row[o] = smean[o];
    } else {
        #pragma unroll
        for (int o = 0; o < 10; ++o) h1row[o] = fmaxf(y[o] + sb1[o], 0.f);
    }

    // layer 2 (10 -> 1). For b==0 all rows share h1row, so mean == value.
    float y2 = 0.f;
    #pragma unroll
    for (int o = 0; o < 10; ++o) y2 += h1row[o] * sW2[o];
    sh2[t] = fmaxf(y2 + b2[0], 0.f);
    __syncthreads();

    // fcg: g[b] = relu(h2_b @ fcgW + fcgb)
    float acc = fcgb[t];
    #pragma unroll 8
    for (int k = 0; k < 128; ++k) acc += sh2[k] * fcgW[k*128 + t];
    g[b*128 + t] = fmaxf(acc, 0.f);
}

// ---------------------------------------------------------------------------
// Kernel 2: fused conv1+conv2 (3x3 SAME, relu both) -> bf16 c2.
// Block: 1 image x 4 output rows. conv1 computed in-block into the LDS halo
// tile (6 rows incl. halo), then conv2 as 5x MFMA 16x16x32 per 16-px tile.
// ---------------------------------------------------------------------------
__global__ __launch_bounds__(256) void conv12_kernel(
    const float* __restrict__ x2,     // (64,128,128)
    const float* __restrict__ w1,     // (16,1,3,3)
    const float* __restrict__ b1,     // (16)
    const float* __restrict__ w2,     // (16,16,3,3)
    const float* __restrict__ b2,     // (16)
    unsigned short* __restrict__ c2bf)// (64,16,128,128) bf16
{
    __shared__ float sx2[8][130];             // 4,160 B  x2 tile (+halo)
    __shared__ unsigned short sin[6*130*16];  // 24,960 B conv1 out [rr][cc][ic]
    __shared__ unsigned short sB[5*512];      // 5,120 B  conv2 B-frags
    __shared__ float sw1[144], sb1v[16];

    int tid = threadIdx.x;
    int blk = blockIdx.x;                     // 64 images * 32 row-groups
    int b   = blk >> 5;
    int R0  = (blk & 31) * 4;

    if (tid < 144) sw1[tid] = w1[tid];
    if (tid < 16)  sb1v[tid] = b1[tid];

    // pack conv2 B-frags: sB[q][lane][e] = w2[oc=lane&15][ic=k&15][dd=2q+(k>>4)]
    for (int idx = tid; idx < 2560; idx += 256) {
        int q   = idx >> 9;
        int rem = idx & 511;
        int l   = rem >> 3;
        int e   = rem & 7;
        int k   = (l >> 4) * 8 + e;    // 0..31
        int oc  = l & 15;
        int ic  = k & 15;
        int dd  = 2*q + (k >> 4);
        unsigned short bits = 0;
        if (dd < 9) bits = f2bf(w2[oc*144 + ic*9 + dd]);
        sB[idx] = bits;
    }
    // zero sin halo columns (cc=0 and cc=129)
    if (tid < 192) {
        int rr = tid >> 5, rem = tid & 31;
        int cc = (rem < 16) ? 0 : 129;
        sin[(rr*130 + cc)*16 + (rem & 15)] = 0;
    }
    // stage x2 rows R0-2 .. R0+5 (zero-padded)
    {
        const float* xb = x2 + (size_t)b * IMG;
        for (int idx = tid; idx < 8*130; idx += 256) {
            int rr = idx / 130, cc = idx - rr*130;
            int ri = R0 - 2 + rr, gj = cc - 1;
            float v = 0.f;
            if (ri >= 0 && ri < 128 && gj >= 0 && gj < 128)
                v = xb[ri*128 + gj];
            sx2[rr][cc] = v;
        }
    }
    __syncthreads();

    // conv1: 6 rows (R0-1..R0+4) x 128 cols x 16 oc -> sin (bf16)
    for (int p = tid; p < 768; p += 256) {
        int rr = p >> 7;            // 0..5 ; conv1 output row = R0-1+rr
        int cc = p & 127;
        int ri1 = R0 - 1 + rr;
        bool valid = (ri1 >= 0 && ri1 < 128);
        float in9[3][3];
        #pragma unroll
        for (int di = 0; di < 3; ++di)
          #pragma unroll
          for (int dj = 0; dj < 3; ++dj)
              in9[di][dj] = sx2[rr + di][cc + dj];
        us8 o0, o1;
        #pragma unroll
        for (int oc = 0; oc < 16; ++oc) {
            float acc = sb1v[oc];
            #pragma unroll
            for (int di = 0; di < 3; ++di)
              #pragma unroll
              for (int dj = 0; dj < 3; ++dj)
                  acc += in9[di][dj] * sw1[oc*9 + di*3 + dj];
            unsigned short bits = valid ? f2bf(fmaxf(acc, 0.f)) : (unsigned short)0;
            if (oc < 8) o0[oc] = bits; else o1[oc - 8] = bits;
        }
        unsigned short* dst = &sin[(rr*130 + cc + 1)*16];
        *reinterpret_cast<us8*>(dst)     = o0;
        *reinterpret_cast<us8*>(dst + 8) = o1;
    }
    __syncthreads();

    // conv2 MFMA
    int lane = tid & 63;
    int wv   = tid >> 6;          // wave id -> output row R0+wv
    int ln   = lane & 15;
    int g    = lane >> 4;
    int ghalf = g & 1;

    int aoff[5];
    #pragma unroll
    for (int q = 0; q < 5; ++q) {
        int dd = 2*q + (g >> 1);
        if (dd > 8) dd = 8;       // B is zero there
        int di = dd / 3, dj = dd % 3;
        aoff[q] = ((wv + di)*130 + ln + dj)*16 + ghalf*8;
    }

    bf16x8 bf[5];
    #pragma unroll
    for (int q = 0; q < 5; ++q)
        bf[q] = *reinterpret_cast<const bf16x8*>(&sB[q*512 + lane*8]);

    float bias_oc = b2[ln];
    int r = R0 + wv;
    unsigned short* outbase = c2bf + ((size_t)b*16 + ln)*IMG + r*128;

    #pragma unroll
    for (int t = 0; t < 8; ++t) {
        f32x4 acc = {0.f, 0.f, 0.f, 0.f};
        #pragma unroll
        for (int q = 0; q < 5; ++q) {
            bf16x8 a = *reinterpret_cast<const bf16x8*>(&sin[aoff[q] + t*256]);
            acc = __builtin_amdgcn_mfma_f32_16x16x32_bf16(a, bf[q], acc, 0, 0, 0);
        }
        int pc = t*16 + g*4;
        us4 pk;
        #pragma unroll
        for (int reg = 0; reg < 4; ++reg)
            pk[reg] = f2bf(fmaxf(acc[reg] + bias_oc, 0.f));
        *reinterpret_cast<us4*>(&outbase[pc]) = pk;   // one 8-B store
    }
}

// ---------------------------------------------------------------------------
// Kernel 3: fcc split-K partials, bf16 MFMA. 512 blocks x K-slice 512.
// W chunk staged TRANSPOSED in LDS via fcc_swz (derived conflict-free on BOTH
// ds_write_b128 staging and ds_read_b128 fragments; fragment = 1 b128 read).
// ---------------------------------------------------------------------------
__global__ __launch_bounds__(256, 3) void fcc_mfma(
    const unsigned short* __restrict__ c2bf, // (64, 262144) bf16 row-major
    const float* __restrict__ W,             // (262144, 128) fp32
    float* __restrict__ partials)            // (512, 64*128)
{
    __shared__ unsigned short sWt[128*128];   // 32 KB, transposed+swizzled

    int tid  = threadIdx.x;
    int blk  = blockIdx.x;
    int k0   = blk * FCC_KRANGE;
    int lane = tid & 63, wv = tid >> 6;
    int ln   = lane & 15, g = lane >> 4;

    int q  = tid & 31;      // staging col-quad (cols 4q..4q+3)
    int kO = tid >> 5;      // staging k-octet group 0..7

    f32x4 acc[8];
    #pragma unroll
    for (int j = 0; j < 8; ++j) acc[j] = (f32x4){0.f,0.f,0.f,0.f};

    const float* Wb = W + (size_t)k0 * 128;
    const unsigned short* arow = c2bf + (size_t)(16*wv + ln)*FCC_K + k0 + g*8;

    for (int ci = 0; ci < 4; ++ci) {
        // ---- stage chunk ci: W rows [ci*128, +128) -> sWt (transposed) ----
        const float* Wc = Wb + (size_t)ci * FCC_CHUNK * 128;
        #pragma unroll
        for (int ko2 = 0; ko2 < 2; ++ko2) {
            int kbase = ko2*64 + kO*8;
            float4 rows[8];
            #pragma unroll
            for (int r = 0; r < 8; ++r)
                rows[r] = *reinterpret_cast<const float4*>(
                    Wc + (size_t)(kbase + r)*128 + q*4);
            us8 vc0, vc1, vc2, vc3;
            #pragma unroll
            for (int r = 0; r < 8; ++r) {
                vc0[r] = f2bf(rows[r].x);
                vc1[r] = f2bf(rows[r].y);
                vc2[r] = f2bf(rows[r].z);
                vc3[r] = f2bf(rows[r].w);
            }
            int col0 = q*4;
            *reinterpret_cast<us8*>(&sWt[fcc_swz(col0+0, kbase)]) = vc0;
            *reinterpret_cast<us8*>(&sWt[fcc_swz(col0+1, kbase)]) = vc1;
            *reinterpret_cast<us8*>(&sWt[fcc_swz(col0+2, kbase)]) = vc2;
            *reinterpret_cast<us8*>(&sWt[fcc_swz(col0+3, kbase)]) = vc3;
        }
        __syncthreads();

        // ---- A-fragments for this chunk (global, L2/L3-resident) ----
        bf16x8 af[4];
        #pragma unroll
        for (int ks = 0; ks < 4; ++ks)
            af[ks] = *reinterpret_cast<const bf16x8*>(arow + ci*FCC_CHUNK + ks*32);

        // ---- compute: 4 K-steps of 32, 8 n-tiles each; 1 b128 per MFMA ----
        #pragma unroll
        for (int ks = 0; ks < 4; ++ks) {
            #pragma unroll
            for (int j = 0; j < 8; ++j) {
                int col = j*16 + ln;
                bf16x8 bfrag = *reinterpret_cast<const bf16x8*>(
                    &sWt[fcc_swz(col, ks*32 + g*8)]);
                acc[j] = __builtin_amdgcn_mfma_f32_16x16x32_bf16(af[ks], bfrag, acc[j], 0, 0, 0);
            }
        }
        __syncthreads();
    }

    float* p = partials + (size_t)blk * 8192;
    #pragma unroll
    for (int j = 0; j < 8; ++j)
      #pragma unroll
      for (int reg = 0; reg < 4; ++reg) {
          int m = 16*wv + g*4 + reg;
          p[m*128 + j*16 + ln] = acc[j][reg];
      }
}

// ---------------------------------------------------------------------------
// Kernel 4: head — 4-way-parallel reduce of partials -> relu(+bias) = c ;
// concat(c,g) -> fc1 relu -> fc2 relu -> fc3 sigmoid. 64 blocks x 512.
// ---------------------------------------------------------------------------
__global__ __launch_bounds__(512) void head_kernel(
    const float* __restrict__ partials, // (512, 64*128)
    const float* __restrict__ fccb,     // (128)
    const float* __restrict__ g,        // (64,128)
    const float* __restrict__ w1, const float* __restrict__ bb1,
    const float* __restrict__ w2, const float* __restrict__ bb2,
    const float* __restrict__ w3, const float* __restrict__ bb3,
    float* __restrict__ out)
{
    __shared__ float sred[4][128];
    __shared__ float sx[256], sh[128], s2[64];
    int b = blockIdx.x, t = threadIdx.x;
    int o = t & 127, pr = t >> 7;      // 4-way K-split over partial slices

    const float* pb = partials + (size_t)pr*8192 + (size_t)b*128 + o;
    float s = 0.f;
    #pragma unroll 8
    for (int p = 0; p < FCC_BLOCKS/4; ++p) s += pb[(size_t)p*4*8192];
    sred[pr][o] = s;
    __syncthreads();

    if (t < 128) {
        sx[t] = fmaxf(sred[0][t] + sred[1][t] + sred[2][t] + sred[3][t]
                      + fccb[t], 0.f);
    } else if (t < 256) {
        sx[t] = g[b*128 + (t - 128)];
    }
    __syncthreads();

    if (t < 128) {
        float acc = bb1[t];
        for (int k = 0; k < 256; ++k) acc += sx[k] * w1[k*128 + t];
        sh[t] = fmaxf(acc, 0.f);
    }
    __syncthreads();
    if (t < 64) {
        float acc = bb2[t];
        for (int k = 0; k < 128; ++k) acc += sh[k] * w2[k*64 + t];
        s2[t] = fmaxf(acc, 0.f);
    }
    __syncthreads();
    if (t < 2) {
        float acc = bb3[t];
        for (int k = 0; k < 64; ++k) acc += s2[k] * w3[k*2 + t];
        out[b*2 + t] = 1.f / (1.f + __expf(-acc));
    }
}

// ---------------------------------------------------------------------------
extern "C" void kernel_launch(void* const* d_in, const int* in_sizes, int n_in,
                              void* d_out, int out_size, void* d_ws, size_t ws_size,
                              hipStream_t stream)
{
    const float* x1      = (const float*)d_in[0];
    const float* x2      = (const float*)d_in[1];
    const float* gcn1_w  = (const float*)d_in[2];
    const float* gcn1_b  = (const float*)d_in[3];
    const float* gcn2_w  = (const float*)d_in[4];
    const float* gcn2_b  = (const float*)d_in[5];
    const float* fcg_w   = (const float*)d_in[6];
    const float* fcg_b   = (const float*)d_in[7];
    const float* conv1_w = (const float*)d_in[8];
    const float* conv1_b = (const float*)d_in[9];
    const float* conv2_w = (const float*)d_in[10];
    const float* conv2_b = (const float*)d_in[11];
    const float* fcc_w   = (const float*)d_in[12];
    const float* fcc_b   = (const float*)d_in[13];
    const float* fc1_w   = (const float*)d_in[14];
    const float* fc1_b   = (const float*)d_in[15];
    const float* fc2_w   = (const float*)d_in[16];
    const float* fc2_b   = (const float*)d_in[17];
    const float* fc3_w   = (const float*)d_in[18];
    const float* fc3_b   = (const float*)d_in[19];
    float* out = (float*)d_out;

    // workspace layout
    float* ws = (float*)d_ws;
    float* g        = ws;                          // 8,192 f
    unsigned short* c2bf = (unsigned short*)(g + 8192);   // 16,777,216 bf16
    float* partials = (float*)(c2bf + 16777216);   // 512*8192 = 4,194,304 f
    // total ~50.4 MB

    gcnfcg_kernel<<<64, 128, 0, stream>>>(x1, gcn1_w, gcn1_b, gcn2_w, gcn2_b,
                                          fcg_w, fcg_b, g);
    conv12_kernel<<<2048, 256, 0, stream>>>(x2, conv1_w, conv1_b,
                                            conv2_w, conv2_b, c2bf);
    fcc_mfma<<<FCC_BLOCKS, 256, 0, stream>>>(c2bf, fcc_w, partials);
    head_kernel<<<64, 512, 0, stream>>>(partials, fcc_b, g, fc1_w, fc1_b,
                                        fc2_w, fc2_b, fc3_w, fc3_b, out);
}

// Round 8
// 90.249 us; speedup vs baseline: 1.5104x; 1.0662x over previous
//
#include <hip/hip_runtime.h>
#include <hip/hip_bf16.h>

// ---------------------------------------------------------------------------
// Model: [conv1+conv2 fused, MFMA] -> fcc(MFMA, pipelined) -> head(+gcn+fcg)
// B=64, K(nodes)=128, N_BAND=5, HW=128, CH=16
// ---------------------------------------------------------------------------

#define NROWS   8192      // B*K
#define IMG     16384     // 128*128
#define FCC_K   262144    // 16*128*128
#define FCC_BLOCKS 512
#define FCC_KRANGE 512    // FCC_K / FCC_BLOCKS
#define FCC_CHUNK 64      // K rows of W per LDS buffer
#define FCC_NCHUNK 8      // FCC_KRANGE / FCC_CHUNK

typedef __attribute__((ext_vector_type(8))) short bf16x8;
typedef __attribute__((ext_vector_type(4))) float f32x4;
typedef __attribute__((ext_vector_type(4))) unsigned short us4;
typedef __attribute__((ext_vector_type(8))) unsigned short us8;

// RNE float->bf16 bits (finite inputs only)
__device__ __forceinline__ unsigned short f2bf(float f) {
    unsigned u = __float_as_uint(f);
    unsigned r = (u + 0x7FFFu + ((u >> 16) & 1u)) >> 16;
    return (unsigned short)r;
}

// fcc LDS layout for one 64x128 chunk (shorts), transposed sWt[col][k].
// idx = col*64 + (k ^ (slot<<3)), slot = ((col>>2)^col)&7.
// Derived conflict-free for BOTH ds_write_b128 staging (slot8 = kO^slot,
// uniform 8 lanes/slot) and ds_read_b128 fragments (slot8 = (ks*4+g)^slot,
// uniform). Bijective per col (XOR with const < 64).
__device__ __forceinline__ int fcc_swz64(int col, int k) {
    return col*64 + (k ^ ((((col >> 2) ^ col) & 7) << 3));
}

// ---------------------------------------------------------------------------
// Kernel 1: fused conv1+conv2 (3x3 SAME, relu both) -> bf16 c2.
// Block: 1 image x 4 output rows. conv1 computed in-block into the LDS halo
// tile (6 rows incl. halo), then conv2 as 5x MFMA 16x16x32 per 16-px tile.
// ---------------------------------------------------------------------------
__global__ __launch_bounds__(256) void conv12_kernel(
    const float* __restrict__ x2,     // (64,128,128)
    const float* __restrict__ w1,     // (16,1,3,3)
    const float* __restrict__ b1,     // (16)
    const float* __restrict__ w2,     // (16,16,3,3)
    const float* __restrict__ b2,     // (16)
    unsigned short* __restrict__ c2bf)// (64,16,128,128) bf16
{
    __shared__ float sx2[8][130];             // 4,160 B  x2 tile (+halo)
    __shared__ unsigned short sin[6*130*16];  // 24,960 B conv1 out [rr][cc][ic]
    __shared__ unsigned short sB[5*512];      // 5,120 B  conv2 B-frags
    __shared__ float sw1[144], sb1v[16];

    int tid = threadIdx.x;
    int blk = blockIdx.x;                     // 64 images * 32 row-groups
    int b   = blk >> 5;
    int R0  = (blk & 31) * 4;

    if (tid < 144) sw1[tid] = w1[tid];
    if (tid < 16)  sb1v[tid] = b1[tid];

    // pack conv2 B-frags: sB[q][lane][e] = w2[oc=lane&15][ic=k&15][dd=2q+(k>>4)]
    for (int idx = tid; idx < 2560; idx += 256) {
        int q   = idx >> 9;
        int rem = idx & 511;
        int l   = rem >> 3;
        int e   = rem & 7;
        int k   = (l >> 4) * 8 + e;    // 0..31
        int oc  = l & 15;
        int ic  = k & 15;
        int dd  = 2*q + (k >> 4);
        unsigned short bits = 0;
        if (dd < 9) bits = f2bf(w2[oc*144 + ic*9 + dd]);
        sB[idx] = bits;
    }
    // zero sin halo columns (cc=0 and cc=129)
    if (tid < 192) {
        int rr = tid >> 5, rem = tid & 31;
        int cc = (rem < 16) ? 0 : 129;
        sin[(rr*130 + cc)*16 + (rem & 15)] = 0;
    }
    // stage x2 rows R0-2 .. R0+5 (zero-padded)
    {
        const float* xb = x2 + (size_t)b * IMG;
        for (int idx = tid; idx < 8*130; idx += 256) {
            int rr = idx / 130, cc = idx - rr*130;
            int ri = R0 - 2 + rr, gj = cc - 1;
            float v = 0.f;
            if (ri >= 0 && ri < 128 && gj >= 0 && gj < 128)
                v = xb[ri*128 + gj];
            sx2[rr][cc] = v;
        }
    }
    __syncthreads();

    // conv1: 6 rows (R0-1..R0+4) x 128 cols x 16 oc -> sin (bf16)
    for (int p = tid; p < 768; p += 256) {
        int rr = p >> 7;            // 0..5 ; conv1 output row = R0-1+rr
        int cc = p & 127;
        int ri1 = R0 - 1 + rr;
        bool valid = (ri1 >= 0 && ri1 < 128);
        float in9[3][3];
        #pragma unroll
        for (int di = 0; di < 3; ++di)
          #pragma unroll
          for (int dj = 0; dj < 3; ++dj)
              in9[di][dj] = sx2[rr + di][cc + dj];
        us8 o0, o1;
        #pragma unroll
        for (int oc = 0; oc < 16; ++oc) {
            float acc = sb1v[oc];
            #pragma unroll
            for (int di = 0; di < 3; ++di)
              #pragma unroll
              for (int dj = 0; dj < 3; ++dj)
                  acc += in9[di][dj] * sw1[oc*9 + di*3 + dj];
            unsigned short bits = valid ? f2bf(fmaxf(acc, 0.f)) : (unsigned short)0;
            if (oc < 8) o0[oc] = bits; else o1[oc - 8] = bits;
        }
        unsigned short* dst = &sin[(rr*130 + cc + 1)*16];
        *reinterpret_cast<us8*>(dst)     = o0;
        *reinterpret_cast<us8*>(dst + 8) = o1;
    }
    __syncthreads();

    // conv2 MFMA
    int lane = tid & 63;
    int wv   = tid >> 6;          // wave id -> output row R0+wv
    int ln   = lane & 15;
    int g    = lane >> 4;
    int ghalf = g & 1;

    int aoff[5];
    #pragma unroll
    for (int q = 0; q < 5; ++q) {
        int dd = 2*q + (g >> 1);
        if (dd > 8) dd = 8;       // B is zero there
        int di = dd / 3, dj = dd % 3;
        aoff[q] = ((wv + di)*130 + ln + dj)*16 + ghalf*8;
    }

    bf16x8 bf[5];
    #pragma unroll
    for (int q = 0; q < 5; ++q)
        bf[q] = *reinterpret_cast<const bf16x8*>(&sB[q*512 + lane*8]);

    float bias_oc = b2[ln];
    int r = R0 + wv;
    unsigned short* outbase = c2bf + ((size_t)b*16 + ln)*IMG + r*128;

    #pragma unroll
    for (int t = 0; t < 8; ++t) {
        f32x4 acc = {0.f, 0.f, 0.f, 0.f};
        #pragma unroll
        for (int q = 0; q < 5; ++q) {
            bf16x8 a = *reinterpret_cast<const bf16x8*>(&sin[aoff[q] + t*256]);
            acc = __builtin_amdgcn_mfma_f32_16x16x32_bf16(a, bf[q], acc, 0, 0, 0);
        }
        int pc = t*16 + g*4;
        us4 pk;
        #pragma unroll
        for (int reg = 0; reg < 4; ++reg)
            pk[reg] = f2bf(fmaxf(acc[reg] + bias_oc, 0.f));
        *reinterpret_cast<us4*>(&outbase[pc]) = pk;   // one 8-B store
    }
}

// ---------------------------------------------------------------------------
// Kernel 2: fcc split-K partials, bf16 MFMA, PIPELINED staging (T14):
// double-buffered 64x128 W chunks; next chunk's global loads are issued
// BEFORE the current chunk's MFMAs and written to LDS after the barrier,
// so the HBM W-stream never drains. 8 float4/thread in flight (no spill).
// ---------------------------------------------------------------------------
__global__ __launch_bounds__(256, 2) void fcc_mfma(
    const unsigned short* __restrict__ c2bf, // (64, 262144) bf16 row-major
    const float* __restrict__ W,             // (262144, 128) fp32
    float* __restrict__ partials)            // (512, 64*128)
{
    __shared__ unsigned short sWt[2][FCC_CHUNK*128];  // 2 x 16 KB

    int tid  = threadIdx.x;
    int blk  = blockIdx.x;
    int k0   = blk * FCC_KRANGE;
    int lane = tid & 63, wv = tid >> 6;
    int ln   = lane & 15, g = lane >> 4;
    int q    = tid & 31;      // staging col-quad (cols 4q..4q+3)
    int kO   = tid >> 5;      // staging k-octet 0..7

    f32x4 acc[8];
    #pragma unroll
    for (int j = 0; j < 8; ++j) acc[j] = (f32x4){0.f,0.f,0.f,0.f};

    const float* Wb = W + (size_t)k0 * 128;
    const unsigned short* arow = c2bf + (size_t)(16*wv + ln)*FCC_K + k0 + g*8;
    int col0 = q*4;

    float4 rows[8];
    bf16x8 afc0, afc1, afn0, afn1;

    // ---- prologue: load + write chunk 0, load its A-frags ----
    #pragma unroll
    for (int r = 0; r < 8; ++r)
        rows[r] = *reinterpret_cast<const float4*>(
            Wb + (size_t)(kO*8 + r)*128 + col0);
    afc0 = *reinterpret_cast<const bf16x8*>(arow);
    afc1 = *reinterpret_cast<const bf16x8*>(arow + 32);
    {
        us8 vc0, vc1, vc2, vc3;
        #pragma unroll
        for (int r = 0; r < 8; ++r) {
            vc0[r] = f2bf(rows[r].x); vc1[r] = f2bf(rows[r].y);
            vc2[r] = f2bf(rows[r].z); vc3[r] = f2bf(rows[r].w);
        }
        *reinterpret_cast<us8*>(&sWt[0][fcc_swz64(col0+0, kO*8)]) = vc0;
        *reinterpret_cast<us8*>(&sWt[0][fcc_swz64(col0+1, kO*8)]) = vc1;
        *reinterpret_cast<us8*>(&sWt[0][fcc_swz64(col0+2, kO*8)]) = vc2;
        *reinterpret_cast<us8*>(&sWt[0][fcc_swz64(col0+3, kO*8)]) = vc3;
    }
    __syncthreads();

    for (int ci = 0; ci < FCC_NCHUNK; ++ci) {
        const unsigned short* bufC = &sWt[ci & 1][0];
        // 1. issue next chunk's loads (stay in flight across compute+barrier)
        if (ci < FCC_NCHUNK-1) {
            const float* Wc = Wb + (size_t)(ci + 1) * FCC_CHUNK * 128;
            #pragma unroll
            for (int r = 0; r < 8; ++r)
                rows[r] = *reinterpret_cast<const float4*>(
                    Wc + (size_t)(kO*8 + r)*128 + col0);
            afn0 = *reinterpret_cast<const bf16x8*>(arow + (ci+1)*FCC_CHUNK);
            afn1 = *reinterpret_cast<const bf16x8*>(arow + (ci+1)*FCC_CHUNK + 32);
        }
        // 2. compute current chunk: 2 K-steps x 8 n-tiles
        #pragma unroll
        for (int j = 0; j < 8; ++j) {
            bf16x8 bfrag = *reinterpret_cast<const bf16x8*>(
                &bufC[fcc_swz64(j*16 + ln, g*8)]);
            acc[j] = __builtin_amdgcn_mfma_f32_16x16x32_bf16(afc0, bfrag, acc[j], 0, 0, 0);
        }
        #pragma unroll
        for (int j = 0; j < 8; ++j) {
            bf16x8 bfrag = *reinterpret_cast<const bf16x8*>(
                &bufC[fcc_swz64(j*16 + ln, 32 + g*8)]);
            acc[j] = __builtin_amdgcn_mfma_f32_16x16x32_bf16(afc1, bfrag, acc[j], 0, 0, 0);
        }
        // 3. all waves done reading bufC's sibling epoch
        __syncthreads();
        // 4. write next chunk into the other buffer
        if (ci < FCC_NCHUNK-1) {
            unsigned short* bufN = &sWt[(ci + 1) & 1][0];
            us8 vc0, vc1, vc2, vc3;
            #pragma unroll
            for (int r = 0; r < 8; ++r) {
                vc0[r] = f2bf(rows[r].x); vc1[r] = f2bf(rows[r].y);
                vc2[r] = f2bf(rows[r].z); vc3[r] = f2bf(rows[r].w);
            }
            *reinterpret_cast<us8*>(&bufN[fcc_swz64(col0+0, kO*8)]) = vc0;
            *reinterpret_cast<us8*>(&bufN[fcc_swz64(col0+1, kO*8)]) = vc1;
            *reinterpret_cast<us8*>(&bufN[fcc_swz64(col0+2, kO*8)]) = vc2;
            *reinterpret_cast<us8*>(&bufN[fcc_swz64(col0+3, kO*8)]) = vc3;
            afc0 = afn0; afc1 = afn1;
        }
        __syncthreads();
    }

    float* p = partials + (size_t)blk * 8192;
    #pragma unroll
    for (int j = 0; j < 8; ++j)
      #pragma unroll
      for (int reg = 0; reg < 4; ++reg) {
          int m = 16*wv + g*4 + reg;
          p[m*128 + j*16 + ln] = acc[j][reg];
      }
}

// ---------------------------------------------------------------------------
// Kernel 3: head — partial-reduce + FULL gcn chain + fcg + MLP head.
// One block per batch row (64 blocks x 512). The GCN mean rows 0..127 are
// exactly batch 0 -> block-local.
// ---------------------------------------------------------------------------
__global__ __launch_bounds__(512) void head_kernel(
    const float* __restrict__ partials, // (512, 64*128)
    const float* __restrict__ fccb,     // (128)
    const float* __restrict__ x1,       // (8192,5)
    const float* __restrict__ gW1,      // (5,10)
    const float* __restrict__ gb1,      // (10)
    const float* __restrict__ gW2,      // (10,1)
    const float* __restrict__ gb2,      // (1)
    const float* __restrict__ fcgW,     // (128,128)
    const float* __restrict__ fcgb,     // (128)
    const float* __restrict__ w1, const float* __restrict__ bb1,
    const float* __restrict__ w2, const float* __restrict__ bb2,
    const float* __restrict__ w3, const float* __restrict__ bb3,
    float* __restrict__ out)
{
    __shared__ float sred[4][128];
    __shared__ float sx[256], sh[128], s2[64], sh2[128];
    __shared__ float sW1[50], sb1s[10], sW2s[10], smean[10];
    __shared__ float sy1[128][10];
    int b = blockIdx.x, t = threadIdx.x;
    int o = t & 127, pr = t >> 7;

    // ---- fcc partial reduce: 4-way K-split, coalesced 512-B rows ----
    {
        const float* pb = partials + (size_t)pr*8192 + (size_t)b*128 + o;
        float s = 0.f;
        #pragma unroll 8
        for (int p = 0; p < FCC_BLOCKS/4; ++p) s += pb[(size_t)p*4*8192];
        sred[pr][o] = s;
    }
    if (t < 50) sW1[t] = gW1[t];
    if (t >= 64 && t < 74) { sb1s[t-64] = gb1[t-64]; sW2s[t-64] = gW2[t-64]; }
    __syncthreads();

    // ---- c = relu(sum partials + fcc_b) ----
    if (t < 128)
        sx[t] = fmaxf(sred[0][t] + sred[1][t] + sred[2][t] + sred[3][t]
                      + fccb[t], 0.f);

    // ---- gcn layer 1 for this batch's 128 rows ----
    float y[10];
    if (t < 128) {
        int r = b*128 + t;
        float x[5];
        #pragma unroll
        for (int f = 0; f < 5; ++f) x[f] = x1[r*5 + f];
        #pragma unroll
        for (int oo = 0; oo < 10; ++oo) {
            float a = 0.f;
            #pragma unroll
            for (int f = 0; f < 5; ++f) a += x[f] * sW1[f*10 + oo];
            y[oo] = a;
        }
    }
    if (b == 0) {                      // block-uniform branch, barriers legal
        if (t < 128) {
            #pragma unroll
            for (int oo = 0; oo < 10; ++oo) sy1[t][oo] = y[oo];
        }
        __syncthreads();
        if (t < 10) {
            float s = 0.f;
            for (int rr = 0; rr < 128; ++rr) s += sy1[rr][t];
            smean[t] = fmaxf(s * (1.f/128.f) + sb1s[t], 0.f);
        }
        __syncthreads();
    }
    if (t < 128) {
        float h1row[10];
        if (b == 0) {
            #pragma unroll
            for (int oo = 0; oo < 10; ++oo) h1row[oo] = smean[oo];
        } else {
            #pragma unroll
            for (int oo = 0; oo < 10; ++oo) h1row[oo] = fmaxf(y[oo] + sb1s[oo], 0.f);
        }
        // layer 2 (10->1); for b==0 all rows identical so mean == value
        float y2 = 0.f;
        #pragma unroll
        for (int oo = 0; oo < 10; ++oo) y2 += h1row[oo] * sW2s[oo];
        sh2[t] = fmaxf(y2 + gb2[0], 0.f);
    }
    __syncthreads();

    // ---- fcg: g = relu(h2 @ fcgW + fcgb) -> sx[128..255] ----
    if (t < 128) {
        float acc = fcgb[t];
        #pragma unroll 8
        for (int k = 0; k < 128; ++k) acc += sh2[k] * fcgW[k*128 + t];
        sx[128 + t] = fmaxf(acc, 0.f);
    }
    __syncthreads();

    // ---- MLP head ----
    if (t < 128) {
        float acc = bb1[t];
        for (int k = 0; k < 256; ++k) acc += sx[k] * w1[k*128 + t];
        sh[t] = fmaxf(acc, 0.f);
    }
    __syncthreads();
    if (t < 64) {
        float acc = bb2[t];
        for (int k = 0; k < 128; ++k) acc += sh[k] * w2[k*64 + t];
        s2[t] = fmaxf(acc, 0.f);
    }
    __syncthreads();
    if (t < 2) {
        float acc = bb3[t];
        for (int k = 0; k < 64; ++k) acc += s2[k] * w3[k*2 + t];
        out[b*2 + t] = 1.f / (1.f + __expf(-acc));
    }
}

// ---------------------------------------------------------------------------
extern "C" void kernel_launch(void* const* d_in, const int* in_sizes, int n_in,
                              void* d_out, int out_size, void* d_ws, size_t ws_size,
                              hipStream_t stream)
{
    const float* x1      = (const float*)d_in[0];
    const float* x2      = (const float*)d_in[1];
    const float* gcn1_w  = (const float*)d_in[2];
    const float* gcn1_b  = (const float*)d_in[3];
    const float* gcn2_w  = (const float*)d_in[4];
    const float* gcn2_b  = (const float*)d_in[5];
    const float* fcg_w   = (const float*)d_in[6];
    const float* fcg_b   = (const float*)d_in[7];
    const float* conv1_w = (const float*)d_in[8];
    const float* conv1_b = (const float*)d_in[9];
    const float* conv2_w = (const float*)d_in[10];
    const float* conv2_b = (const float*)d_in[11];
    const float* fcc_w   = (const float*)d_in[12];
    const float* fcc_b   = (const float*)d_in[13];
    const float* fc1_w   = (const float*)d_in[14];
    const float* fc1_b   = (const float*)d_in[15];
    const float* fc2_w   = (const float*)d_in[16];
    const float* fc2_b   = (const float*)d_in[17];
    const float* fc3_w   = (const float*)d_in[18];
    const float* fc3_b   = (const float*)d_in[19];
    float* out = (float*)d_out;

    // workspace layout
    unsigned short* c2bf = (unsigned short*)d_ws;          // 16,777,216 bf16
    float* partials = (float*)(c2bf + 16777216);           // 4,194,304 f
    // total ~48.2 MB

    conv12_kernel<<<2048, 256, 0, stream>>>(x2, conv1_w, conv1_b,
                                            conv2_w, conv2_b, c2bf);
    fcc_mfma<<<FCC_BLOCKS, 256, 0, stream>>>(c2bf, fcc_w, partials);
    head_kernel<<<64, 512, 0, stream>>>(partials, fcc_b,
                                        x1, gcn1_w, gcn1_b, gcn2_w, gcn2_b,
                                        fcg_w, fcg_b,
                                        fc1_w, fc1_b, fc2_w, fc2_b,
                                        fc3_w, fc3_b, out);
}